// Round 19
// baseline (382.676 us; speedup 1.0000x reference)
//
#include <hip/hip_runtime.h>

static constexpr int T_LEN = 1024;

typedef _Float16 f16;
typedef f16  f16x4 __attribute__((ext_vector_type(4)));
typedef f16  f16x8 __attribute__((ext_vector_type(8)));
typedef float f32x4 __attribute__((ext_vector_type(4)));

__device__ __forceinline__ f32x4 mfma_k32(f16x8 a, f16x8 b, f32x4 c) {
    return __builtin_amdgcn_mfma_f32_16x16x32_f16(a, b, c, 0, 0, 0);
}
// 1/(1+2^t): overflow-safe (t->+inf: exp2=inf, rcp->0; t->-inf: ->1)
__device__ __forceinline__ float sig2(float t) {
    return __builtin_amdgcn_rcpf(1.f + __builtin_amdgcn_exp2f(t));
}

// Round-19: R18's issue shave (peeled t=0, precomputed ping-pong pointers,
// hoisted ci) + R17's conflict-free LDS layouts restored:
//  - hx rows 36 f16 (stride 18 dwords -> 16 mixed-parity bank bases,
//    R17-measured ~0 conflicts; R18's 40 gave 12.6M)
//  - x tile f16, row stride 1028 f16 = 514 dwords (% 32 == 2, clean)
// Arithmetic bit-identical to R17/R18.
//
// Structure (R17-verified): 8 waves, 16 seqs, one mfma_f32_16x16x32_f16
// per wave-step computes BOTH layers' gates of this wave's 2 units
// (A rows: L1 [Whh0|0], L2 [Wih1|Whh1]; B: [h1[t-1] | h2[t-2]] octets);
// lane-local LSTM update; single f16 write + barrier + b128 read per step.
__global__ void __launch_bounds__(512, 1) lstm2_k32c_kernel(
    const float* __restrict__ x,
    const float* __restrict__ Wih0, const float* __restrict__ Whh0,
    const float* __restrict__ bih0, const float* __restrict__ bhh0,
    const float* __restrict__ Wih1, const float* __restrict__ Whh1,
    const float* __restrict__ bih1, const float* __restrict__ bhh1,
    const float* __restrict__ Wout, const float* __restrict__ bout,
    float* __restrict__ out)
{
    const int tid  = threadIdx.x;
    const int w    = tid >> 6;         // wave 0..7: units {2w,2w+1}, both layers
    const int l    = tid & 63;
    const int n    = l & 15;           // seq col (B/D); A tile-row
    const int Lq   = l >> 4;           // k-octet / D row-quad
    const int isL2 = Lq >> 1;          // 0: L1-role lanes, 1: L2-role lanes
    const int u2   = 2 * w + (Lq & 1); // owned unit
    const int seq  = blockIdx.x * 16 + n;

    // x tile, f16: stride 1028 f16 = 514 dwords (%32==2) -> conflict-free.
    __shared__ __align__(16) f16   x_lds[16][1028];
    // h exchange: [slot][seq][36 f16]: 0-15 h1 units, 16-31 h2, 32-35 pad.
    __shared__ __align__(16) f16   hx[2][16][36];
    __shared__ __align__(16) float h2fin[16][20];

    // ---- stage x (f32 global -> f16 LDS), coalesced, once.
    {
        const float* xblk = x + (size_t)blockIdx.x * 16 * T_LEN;
#pragma unroll
        for (int jj = 0; jj < 8; ++jj) {
            const int flat = jj * 2048 + tid * 4;      // f32 quad index
            const int row  = flat >> 10, col = flat & 1023;
            const float4 v = *reinterpret_cast<const float4*>(
                xblk + (size_t)row * T_LEN + col);
            f16x4 h4; h4[0] = (f16)v.x; h4[1] = (f16)v.y;
                      h4[2] = (f16)v.z; h4[3] = (f16)v.w;
            *reinterpret_cast<f16x4*>(&x_lds[row][col]) = h4;
        }
    }

    const float L2E = 1.442695041f;
    const float NT  = -2.f * L2E;      // tanh(c) scale

    // ---- A-fragment (8 f16): tile-row m = n, k = 8*Lq + j (R17-verified).
    const int   mh  = n >> 2, mg = n & 3;
    const float nsm = (mg == 2) ? (-2.f * L2E) : (-L2E);
    f16x8 WA;
#pragma unroll
    for (int j = 0; j < 8; ++j) {
        const int k = 8 * Lq + j;
        float wv;
        if (mh < 2) {                  // L1 rows: [Whh0 | 0]
            const int wr = mg * 16 + 2 * w + mh;
            wv = (k < 16) ? Whh0[wr * 16 + k] : 0.f;
        } else {                       // L2 rows: [Wih1 | Whh1]
            const int wr = mg * 16 + 2 * w + (mh - 2);
            wv = (k < 16) ? Wih1[wr * 16 + k] : Whh1[wr * 16 + (k - 16)];
        }
        WA[j] = (f16)(nsm * wv);
    }
    // ---- D-side constants: acc reg r = gate r of (layer isL2, unit u2).
    f32x4 cbD, wxD;
#pragma unroll
    for (int r = 0; r < 4; ++r) {
        const float nsD = (r == 2) ? (-2.f * L2E) : (-L2E);
        const int   row = r * 16 + u2;
        if (!isL2) {
            cbD[r] = nsD * (bih0[row] + bhh0[row]);
            wxD[r] = nsD * Wih0[row];
        } else {
            cbD[r] = nsD * (bih1[row] + bhh1[row]);
            wxD[r] = 0.f;
        }
    }
    asm volatile("" : "+v"(WA), "+v"(cbD), "+v"(wxD));

    // ---- precomputed ping-pong exchange pointers.
    f16* const wp0 = &hx[0][n][isL2 * 16 + u2];
    f16* const wp1 = &hx[1][n][isL2 * 16 + u2];
    const f16x8* const rp0 = reinterpret_cast<const f16x8*>(&hx[0][n][8 * Lq]);
    const f16x8* const rp1 = reinterpret_cast<const f16x8*>(&hx[1][n][8 * Lq]);

    f16x8 rh = {};                     // B-slice: [h1[t-1] | h2[t-2]] octet
    float cc = 0.f;                    // c1 (L1 lanes) / c2 (L2 lanes)

    __syncthreads();                   // x staged; orders weight loads

// one step: MFMA + lane-local update + exchange. MASK0 is compile-time.
#define LSTM_STEP(UIDX, CIV, MASK0)                                   \
    {                                                                 \
        const f32x4 d = mfma_k32(WA, rh, (CIV));                      \
        const float si = sig2(d[0]);                                  \
        const float sf = sig2(d[1]);                                  \
        const float sg = fmaf(2.f, sig2(d[2]), -1.f);                 \
        const float so = sig2(d[3]);                                  \
        float ccn = fmaf(sf, cc, si * sg);                            \
        const float th = fmaf(2.f, sig2(NT * ccn), -1.f);             \
        float hv = so * th;                                           \
        if (MASK0 && isL2) { ccn = 0.f; hv = 0.f; }                   \
        cc = ccn;                                                     \
        *(((UIDX) & 1) ? wp1 : wp0) = (f16)hv;                        \
        __syncthreads();                                              \
        rh = *(((UIDX) & 1) ? rp1 : rp0);                             \
    }

    // ---- first window (t = 0..3): mask fake L2 step -1 at t=0.
    f16x4 xw = *reinterpret_cast<const f16x4*>(&x_lds[n][0]);
    f16x4 xnx = *reinterpret_cast<const f16x4*>(&x_lds[n][4]);
    {
        f32x4 ci0, ci1, ci2, ci3;
        const float x0 = (float)xw[0], x1 = (float)xw[1];
        const float x2 = (float)xw[2], x3 = (float)xw[3];
#pragma unroll
        for (int r = 0; r < 4; ++r) {
            ci0[r] = fmaf(wxD[r], x0, cbD[r]);
            ci1[r] = fmaf(wxD[r], x1, cbD[r]);
            ci2[r] = fmaf(wxD[r], x2, cbD[r]);
            ci3[r] = fmaf(wxD[r], x3, cbD[r]);
        }
        LSTM_STEP(0, ci0, true)
        LSTM_STEP(1, ci1, false)
        LSTM_STEP(2, ci2, false)
        LSTM_STEP(3, ci3, false)
    }
    xw = xnx;

    // ---- steady loop (t = 4..1023), no masks, pointers precomputed.
    for (int tb = 4; tb < T_LEN; tb += 4) {
        f16x4 xn2 = xw;
        if (tb + 4 < T_LEN)
            xn2 = *reinterpret_cast<const f16x4*>(&x_lds[n][tb + 4]);
        f32x4 ci0, ci1, ci2, ci3;
        const float x0 = (float)xw[0], x1 = (float)xw[1];
        const float x2 = (float)xw[2], x3 = (float)xw[3];
#pragma unroll
        for (int r = 0; r < 4; ++r) {
            ci0[r] = fmaf(wxD[r], x0, cbD[r]);
            ci1[r] = fmaf(wxD[r], x1, cbD[r]);
            ci2[r] = fmaf(wxD[r], x2, cbD[r]);
            ci3[r] = fmaf(wxD[r], x3, cbD[r]);
        }
        LSTM_STEP(0, ci0, false)
        LSTM_STEP(1, ci1, false)
        LSTM_STEP(2, ci2, false)
        LSTM_STEP(3, ci3, false)
        xw = xn2;
    }
#undef LSTM_STEP

    // ---- epilogue: L2 step 1023 from rh = [h1[1023] | h2[1022]].
    {
        const f32x4 d = mfma_k32(WA, rh, cbD);
        const float si = sig2(d[0]);
        const float sf = sig2(d[1]);
        const float sg = fmaf(2.f, sig2(d[2]), -1.f);
        const float so = sig2(d[3]);
        const float c2f = fmaf(sf, cc, si * sg);
        const float th  = fmaf(2.f, sig2(NT * c2f), -1.f);
        if (isL2) h2fin[n][u2] = so * th;      // f32 for the head
    }
    __syncthreads();

    // ---- head (wave 0): out[seq][m] = relu(h2) . Wout[m] + bout[m]
    if (w == 0) {
        const f32x4 hv4 = *reinterpret_cast<const f32x4*>(&h2fin[n][4 * Lq]);
#pragma unroll
        for (int m5 = 0; m5 < 5; ++m5) {
            float p = 0.f;
#pragma unroll
            for (int r = 0; r < 4; ++r)
                p = fmaf(fmaxf(hv4[r], 0.f), Wout[m5 * 16 + 4 * Lq + r], p);
            p += __shfl_xor(p, 16, 64);
            p += __shfl_xor(p, 32, 64);
            if (Lq == 0) out[seq * 5 + m5] = p + bout[m5];
        }
    }
}

extern "C" void kernel_launch(void* const* d_in, const int* in_sizes, int n_in,
                              void* d_out, int out_size, void* d_ws, size_t ws_size,
                              hipStream_t stream) {
    const float* x    = (const float*)d_in[0];
    const float* Wih0 = (const float*)d_in[1];
    const float* Whh0 = (const float*)d_in[2];
    const float* bih0 = (const float*)d_in[3];
    const float* bhh0 = (const float*)d_in[4];
    const float* Wih1 = (const float*)d_in[5];
    const float* Whh1 = (const float*)d_in[6];
    const float* bih1 = (const float*)d_in[7];
    const float* bhh1 = (const float*)d_in[8];
    const float* Wout = (const float*)d_in[9];
    const float* bout = (const float*)d_in[10];
    float* out = (float*)d_out;

    const int B = in_sizes[0] / T_LEN;          // 4096
    dim3 grid(B / 16), block(512);              // 8 uniform waves / 16 seqs
    hipLaunchKernelGGL(lstm2_k32c_kernel, grid, block, 0, stream,
                       x, Wih0, Whh0, bih0, bhh0,
                       Wih1, Whh1, bih1, bhh1, Wout, bout, out);
}

// Round 20
// 240.305 us; speedup vs baseline: 1.5925x; 1.5925x over previous
//
#include <hip/hip_runtime.h>

static constexpr int T_LEN = 1024;

typedef _Float16 f16;
typedef f16  f16x4 __attribute__((ext_vector_type(4)));
typedef f16  f16x8 __attribute__((ext_vector_type(8)));
typedef float f32x4 __attribute__((ext_vector_type(4)));

__device__ __forceinline__ f32x4 mfma_k32(f16x8 a, f16x8 b, f32x4 c) {
    return __builtin_amdgcn_mfma_f32_16x16x32_f16(a, b, c, 0, 0, 0);
}
// 1/(1+2^t): overflow-safe (t->+inf: exp2=inf, rcp->0; t->-inf: ->1)
__device__ __forceinline__ float sig2(float t) {
    return __builtin_amdgcn_rcpf(1.f + __builtin_amdgcn_exp2f(t));
}

// Round-20: exact revert to Round-18 (measured best, 240.1 µs).
//  - K32 one-MFMA-per-wave-step (R17 structure): A rows = L1 [Whh0|0] and
//    L2 [Wih1|Whh1] interleaved; B = [h1[t-1] | h2[t-2]] octets; lane-local
//    LSTM update (R10 row permutation); tanh gate = compile-time reg 2.
//  - t=0 peeled (no per-step mask), ping-pong LDS pointers precomputed,
//    ci hoisted per 4-step window, x kept f32 in LDS.
//  - hx rows 40 f16 (80 B): 16B-ALIGNED b128 octet reads. The 2-way write
//    conflicts this stride causes (~12.6M counts) are hidden in the DS
//    pipe; R19 proved misaligned (8B) b128 reads on the exchange chain
//    cost far more (240 -> 382 µs).
__global__ void __launch_bounds__(512, 1) lstm2_k32b_kernel(
    const float* __restrict__ x,
    const float* __restrict__ Wih0, const float* __restrict__ Whh0,
    const float* __restrict__ bih0, const float* __restrict__ bhh0,
    const float* __restrict__ Wih1, const float* __restrict__ Whh1,
    const float* __restrict__ bih1, const float* __restrict__ bhh1,
    const float* __restrict__ Wout, const float* __restrict__ bout,
    float* __restrict__ out)
{
    const int tid  = threadIdx.x;
    const int w    = tid >> 6;         // wave 0..7: units {2w,2w+1}, both layers
    const int l    = tid & 63;
    const int n    = l & 15;           // seq col (B/D); A tile-row
    const int Lq   = l >> 4;           // k-octet / D row-quad
    const int isL2 = Lq >> 1;          // 0: L1-role lanes, 1: L2-role lanes
    const int u2   = 2 * w + (Lq & 1); // owned unit
    const int seq  = blockIdx.x * 16 + n;

    // x tile, f32: stride 1028 dwords -> b128 reads bank-spread (2-way max).
    __shared__ __align__(16) float x_lds[16][1028];
    // h exchange: [slot][seq][40 f16] = 80B rows (16B-aligned octets).
    __shared__ __align__(16) f16   hx[2][16][40];
    __shared__ __align__(16) float h2fin[16][20];

    // ---- stage x (f32 global -> f32 LDS), coalesced, once.
    {
        const float* xblk = x + (size_t)blockIdx.x * 16 * T_LEN;
#pragma unroll
        for (int jj = 0; jj < 8; ++jj) {
            const int flat = jj * 2048 + tid * 4;      // f32 quad index
            const int row  = flat >> 10, col = flat & 1023;
            const float4 v = *reinterpret_cast<const float4*>(
                xblk + (size_t)row * T_LEN + col);
            *reinterpret_cast<float4*>(&x_lds[row][col]) = v;
        }
    }

    const float L2E = 1.442695041f;
    const float NT  = -2.f * L2E;      // tanh(c) scale

    // ---- A-fragment (8 f16): tile-row m = n, k = 8*Lq + j (R17-verified).
    const int   mh  = n >> 2, mg = n & 3;
    const float nsm = (mg == 2) ? (-2.f * L2E) : (-L2E);
    f16x8 WA;
#pragma unroll
    for (int j = 0; j < 8; ++j) {
        const int k = 8 * Lq + j;
        float wv;
        if (mh < 2) {                  // L1 rows: [Whh0 | 0]
            const int wr = mg * 16 + 2 * w + mh;
            wv = (k < 16) ? Whh0[wr * 16 + k] : 0.f;
        } else {                       // L2 rows: [Wih1 | Whh1]
            const int wr = mg * 16 + 2 * w + (mh - 2);
            wv = (k < 16) ? Wih1[wr * 16 + k] : Whh1[wr * 16 + (k - 16)];
        }
        WA[j] = (f16)(nsm * wv);
    }
    // ---- D-side constants: acc reg r = gate r of (layer isL2, unit u2).
    f32x4 cbD, wxD;
#pragma unroll
    for (int r = 0; r < 4; ++r) {
        const float nsD = (r == 2) ? (-2.f * L2E) : (-L2E);
        const int   row = r * 16 + u2;
        if (!isL2) {
            cbD[r] = nsD * (bih0[row] + bhh0[row]);
            wxD[r] = nsD * Wih0[row];
        } else {
            cbD[r] = nsD * (bih1[row] + bhh1[row]);
            wxD[r] = 0.f;
        }
    }
    asm volatile("" : "+v"(WA), "+v"(cbD), "+v"(wxD));

    // ---- precomputed ping-pong exchange pointers.
    f16* const wp0 = &hx[0][n][isL2 * 16 + u2];
    f16* const wp1 = &hx[1][n][isL2 * 16 + u2];
    const f16x8* const rp0 = reinterpret_cast<const f16x8*>(&hx[0][n][8 * Lq]);
    const f16x8* const rp1 = reinterpret_cast<const f16x8*>(&hx[1][n][8 * Lq]);

    f16x8 rh = {};                     // B-slice: [h1[t-1] | h2[t-2]] octet
    float cc = 0.f;                    // c1 (L1 lanes) / c2 (L2 lanes)

    __syncthreads();                   // x staged; orders weight loads

// one step: MFMA + lane-local update + exchange. MASK0 is compile-time.
#define LSTM_STEP(UIDX, CIV, MASK0)                                   \
    {                                                                 \
        const f32x4 d = mfma_k32(WA, rh, (CIV));                      \
        const float si = sig2(d[0]);                                  \
        const float sf = sig2(d[1]);                                  \
        const float sg = fmaf(2.f, sig2(d[2]), -1.f);                 \
        const float so = sig2(d[3]);                                  \
        float ccn = fmaf(sf, cc, si * sg);                            \
        const float th = fmaf(2.f, sig2(NT * ccn), -1.f);             \
        float hv = so * th;                                           \
        if (MASK0 && isL2) { ccn = 0.f; hv = 0.f; }                   \
        cc = ccn;                                                     \
        *(((UIDX) & 1) ? wp1 : wp0) = (f16)hv;                        \
        __syncthreads();                                              \
        rh = *(((UIDX) & 1) ? rp1 : rp0);                             \
    }

    // ---- first window (t = 0..3): mask fake L2 step -1 at t=0.
    float4 xw = *reinterpret_cast<const float4*>(&x_lds[n][0]);
    float4 xnx = *reinterpret_cast<const float4*>(&x_lds[n][4]);
    {
        f32x4 ci0, ci1, ci2, ci3;
#pragma unroll
        for (int r = 0; r < 4; ++r) {
            ci0[r] = fmaf(wxD[r], xw.x, cbD[r]);
            ci1[r] = fmaf(wxD[r], xw.y, cbD[r]);
            ci2[r] = fmaf(wxD[r], xw.z, cbD[r]);
            ci3[r] = fmaf(wxD[r], xw.w, cbD[r]);
        }
        LSTM_STEP(0, ci0, true)
        LSTM_STEP(1, ci1, false)
        LSTM_STEP(2, ci2, false)
        LSTM_STEP(3, ci3, false)
    }
    xw = xnx;

    // ---- steady loop (t = 4..1023), no masks, pointers precomputed.
    for (int tb = 4; tb < T_LEN; tb += 4) {
        float4 xn2 = xw;
        if (tb + 4 < T_LEN)
            xn2 = *reinterpret_cast<const float4*>(&x_lds[n][tb + 4]);
        f32x4 ci0, ci1, ci2, ci3;
#pragma unroll
        for (int r = 0; r < 4; ++r) {
            ci0[r] = fmaf(wxD[r], xw.x, cbD[r]);
            ci1[r] = fmaf(wxD[r], xw.y, cbD[r]);
            ci2[r] = fmaf(wxD[r], xw.z, cbD[r]);
            ci3[r] = fmaf(wxD[r], xw.w, cbD[r]);
        }
        LSTM_STEP(0, ci0, false)
        LSTM_STEP(1, ci1, false)
        LSTM_STEP(2, ci2, false)
        LSTM_STEP(3, ci3, false)
        xw = xn2;
    }
#undef LSTM_STEP

    // ---- epilogue: L2 step 1023 from rh = [h1[1023] | h2[1022]].
    {
        const f32x4 d = mfma_k32(WA, rh, cbD);
        const float si = sig2(d[0]);
        const float sf = sig2(d[1]);
        const float sg = fmaf(2.f, sig2(d[2]), -1.f);
        const float so = sig2(d[3]);
        const float c2f = fmaf(sf, cc, si * sg);
        const float th  = fmaf(2.f, sig2(NT * c2f), -1.f);
        if (isL2) h2fin[n][u2] = so * th;      // f32 for the head
    }
    __syncthreads();

    // ---- head (wave 0): out[seq][m] = relu(h2) . Wout[m] + bout[m]
    if (w == 0) {
        const f32x4 hv4 = *reinterpret_cast<const f32x4*>(&h2fin[n][4 * Lq]);
#pragma unroll
        for (int m5 = 0; m5 < 5; ++m5) {
            float p = 0.f;
#pragma unroll
            for (int r = 0; r < 4; ++r)
                p = fmaf(fmaxf(hv4[r], 0.f), Wout[m5 * 16 + 4 * Lq + r], p);
            p += __shfl_xor(p, 16, 64);
            p += __shfl_xor(p, 32, 64);
            if (Lq == 0) out[seq * 5 + m5] = p + bout[m5];
        }
    }
}

extern "C" void kernel_launch(void* const* d_in, const int* in_sizes, int n_in,
                              void* d_out, int out_size, void* d_ws, size_t ws_size,
                              hipStream_t stream) {
    const float* x    = (const float*)d_in[0];
    const float* Wih0 = (const float*)d_in[1];
    const float* Whh0 = (const float*)d_in[2];
    const float* bih0 = (const float*)d_in[3];
    const float* bhh0 = (const float*)d_in[4];
    const float* Wih1 = (const float*)d_in[5];
    const float* Whh1 = (const float*)d_in[6];
    const float* bih1 = (const float*)d_in[7];
    const float* bhh1 = (const float*)d_in[8];
    const float* Wout = (const float*)d_in[9];
    const float* bout = (const float*)d_in[10];
    float* out = (float*)d_out;

    const int B = in_sizes[0] / T_LEN;          // 4096
    dim3 grid(B / 16), block(512);              // 8 uniform waves / 16 seqs
    hipLaunchKernelGGL(lstm2_k32b_kernel, grid, block, 0, stream,
                       x, Wih0, Whh0, bih0, bhh0,
                       Wih1, Whh1, bih1, bhh1, Wout, bout, out);
}